// Round 17
// baseline (228.448 us; speedup 1.0000x reference)
//
#include <hip/hip_runtime.h>
#include <hip/hip_bf16.h>
#include <stdint.h>

typedef __attribute__((ext_vector_type(8))) short bf16x8;   // 8 bf16 = 4 VGPRs
typedef __attribute__((ext_vector_type(4))) short s16x4;    // 4 bf16 = 8 B
typedef __attribute__((ext_vector_type(4))) float f32x4;

#define THREADS 256
constexpr int NWIN = 2304;

// d_ws layout (bf16 element offsets)
constexpr int WCATT_E = 0;        // [1536][64]  : col n of [Wq*0.125|Wkv_k|Wkv_v], 64 k contiguous
constexpr int WOT_E   = 98304;    // [64][512]   : col n of Wo, 512 k contiguous
constexpr int POS_E   = 131072;   // [8][64][64]
constexpr size_t WS_NEED = 327680; // bytes

__device__ __forceinline__ short f2bf(float f) {
  __hip_bfloat16 h = __float2bfloat16(f);
  return __builtin_bit_cast(short, h);
}
__device__ __forceinline__ float bf2f(short s) {
  uint32_t u = ((uint32_t)(uint16_t)s) << 16;
  return __builtin_bit_cast(float, u);
}
// 16B-slot XOR key; same involution on write and read sides.
__device__ __forceinline__ int swz(int row, int h) {
  return ((((row ^ (row >> 2) ^ (row >> 3)) & 7) ^ h) << 4);
}

// ---------------- prep: weights -> bf16 transposed in ws ----------------
__global__ void wmsa_prep(const float* __restrict__ Wq, const float* __restrict__ Wkv,
                          const float* __restrict__ Wo, const float* __restrict__ pos,
                          short* __restrict__ ws) {
  int idx = blockIdx.x * 256 + threadIdx.x;
  if (idx < 32768) {                       // Wq -> WcatT[n][k], pre-scaled by 0.125
    int n = idx & 511, k = idx >> 9;
    ws[WCATT_E + n * 64 + k] = f2bf(Wq[k * 512 + n] * 0.125f);
  } else if (idx < 98304) {                // Wkv -> WcatT[512+nkv][k]
    int j = idx - 32768;
    int nkv = j & 1023, k = j >> 10;
    ws[WCATT_E + (512 + nkv) * 64 + k] = f2bf(Wkv[k * 1024 + nkv]);
  } else if (idx < 131072) {               // Wo -> WoT[n][k]
    int j = idx - 98304;
    int n = j & 63, k = j >> 6;
    ws[WOT_E + n * 512 + k] = f2bf(Wo[k * 64 + n]);
  } else if (idx < 163840) {               // pos -> bf16 (natural [h][i][j])
    int j = idx - 131072;
    ws[POS_E + j] = f2bf(pos[j]);
  }
}

// ======== G=4 pair-pipelined kernel: pair A (win 0,1) / pair B (win 2,3) ========
// Every barrier segment mixes one pair's global-load GEMM with the other pair's
// LDS attention so load latency hides under compute. Index maps = R12 verified.
// LDS: win*32768 + { QP [0,16K) (Q->P->OH), KV [16K,32K) }; 128 KB, 1 block/CU.
__global__ __launch_bounds__(512, 2)
void wmsa_pipe(const float* __restrict__ x, const float* __restrict__ bo,
               const short* __restrict__ ws, float* __restrict__ out) {
  extern __shared__ __align__(16) char lds[];
  const int tid = threadIdx.x;
  const int wv = tid >> 6;       // 0..7
  const int l  = tid & 63;
  const int lr = l & 15;
  const int lg = l >> 4;

  const int bid = blockIdx.x;
  const int q   = bid >> 2;          // window quad 0..575
  const int hp  = bid & 3;           // head-pair

  const int bq = wv & 3, aq = wv >> 2;
  const int aw = aq;                 // attention window-in-pair (0/1)
  const int hl = (wv >> 1) & 1;
  const int ih = wv & 1;
  const int hglob = 2 * hp + hl;

  // ---- X fragments for all 4 windows ----
  bf16x8 xa[4][2];
  #pragma unroll
  for (int win = 0; win < 4; ++win) {
    int w   = 4 * q + win;
    int bb  = w / 576;
    int rem = (w % 576) * 64;
    int hh  = rem / 192;
    int ww0 = rem % 192;
    int src_h = (hh + 4) % 192;
    const float* xp = x + (size_t)(bb * 192 + src_h) * 12288;
    int tok = 16 * hp + lr;
    int sw = ww0 + tok + 4; if (sw >= 192) sw -= 192;
    const float* xq = xp + sw * 64;
    #pragma unroll
    for (int ks = 0; ks < 2; ++ks) {
      float4 a = *(const float4*)(xq + ks * 32 + lg * 8);
      float4 b = *(const float4*)(xq + ks * 32 + lg * 8 + 4);
      bf16x8 v;
      v[0] = f2bf(a.x); v[1] = f2bf(a.y); v[2] = f2bf(a.z); v[3] = f2bf(a.w);
      v[4] = f2bf(b.x); v[5] = f2bf(b.y); v[6] = f2bf(b.z); v[7] = f2bf(b.w);
      xa[win][ks] = v;
    }
  }

  // pos fragments (loop-invariant)
  s16x4 posr[2][4];
  #pragma unroll
  for (int it = 0; it < 2; ++it) {
    int i = (ih * 2 + it) * 16 + lr;
    const short* pp = ws + POS_E + hglob * 4096 + i * 64;
    #pragma unroll
    for (int jt = 0; jt < 4; ++jt)
      posr[it][jt] = *(const s16x4*)(pp + jt * 16 + lg * 4);
  }

  // ======== Seg1: P1(A) = QK-GEMM(win0,1) + V-GEMM(A)->regs ========
  #pragma unroll
  for (int t = 0; t < 8; ++t) {
    int nt = wv + 8 * t;
    int nload = nt * 16 + lr;
    bf16x8 b0 = *(const bf16x8*)(ws + WCATT_E + nload * 64 + lg * 8);
    bf16x8 b1 = *(const bf16x8*)(ws + WCATT_E + nload * 64 + 32 + lg * 8);
    const bool isQ = (t < 4);
    int i  = (lr & 7) * 8 + ((nt >> 2) & 7);
    int h2 = lr >> 3;
    int d0 = (nt & 3) * 16 + lg * 4;
    int off = (isQ ? 0 : 16384) + h2 * 8192 + i * 128 + ((d0 * 2) ^ swz(i, h2));
    #pragma unroll
    for (int win = 0; win < 2; ++win) {
      f32x4 acc = {0.f, 0.f, 0.f, 0.f};
      acc = __builtin_amdgcn_mfma_f32_16x16x32_bf16(b0, xa[win][0], acc, 0, 0, 0);
      acc = __builtin_amdgcn_mfma_f32_16x16x32_bf16(b1, xa[win][1], acc, 0, 0, 0);
      s16x4 pk;
      #pragma unroll
      for (int r = 0; r < 4; ++r) pk[r] = f2bf(acc[r]);
      *(s16x4*)(lds + win * 32768 + off) = pk;
    }
  }
  f32x4 vaccA[2][4];
  #pragma unroll
  for (int u = 0; u < 4; ++u) {
    int ntile = (aq * 4 + u) * 4 + bq;
    int nload = (64 + ntile) * 16 + lr;
    bf16x8 b0 = *(const bf16x8*)(ws + WCATT_E + nload * 64 + lg * 8);
    bf16x8 b1 = *(const bf16x8*)(ws + WCATT_E + nload * 64 + 32 + lg * 8);
    #pragma unroll
    for (int win = 0; win < 2; ++win) {
      f32x4 acc = {0.f, 0.f, 0.f, 0.f};
      acc = __builtin_amdgcn_mfma_f32_16x16x32_bf16(xa[win][0], b0, acc, 0, 0, 0);
      acc = __builtin_amdgcn_mfma_f32_16x16x32_bf16(xa[win][1], b1, acc, 0, 0, 0);
      vaccA[win][u] = acc;
    }
  }
  __syncthreads();                      // bar1: Q,K(A) in LDS

  // ======== Seg2: B-loads issued early; QK^T(A); QK(B) consume; softmax(A); V(B) ========
  char* ldwA = lds + aw * 32768;

  // (1) issue QK(B) weight batch (in flight under QK^T(A))
  bf16x8 qkw[8][2];
  #pragma unroll
  for (int t = 0; t < 8; ++t) {
    int nload = (wv + 8 * t) * 16 + lr;
    qkw[t][0] = *(const bf16x8*)(ws + WCATT_E + nload * 64 + lg * 8);
    qkw[t][1] = *(const bf16x8*)(ws + WCATT_E + nload * 64 + 32 + lg * 8);
  }

  // (2) QK^T(A)
  f32x4 sA[2][4];
  #pragma unroll
  for (int it = 0; it < 2; ++it)
    #pragma unroll
    for (int jt = 0; jt < 4; ++jt) sA[it][jt] = (f32x4){0.f, 0.f, 0.f, 0.f};
  #pragma unroll
  for (int ks = 0; ks < 2; ++ks) {
    bf16x8 kb[4], qa[2];
    #pragma unroll
    for (int jt = 0; jt < 4; ++jt) {
      int j = jt * 16 + lr;
      kb[jt] = *(const bf16x8*)(ldwA + 16384 + hl * 8192 + j * 128 + ((ks * 64 + lg * 16) ^ swz(j, hl)));
    }
    #pragma unroll
    for (int it = 0; it < 2; ++it) {
      int i = (ih * 2 + it) * 16 + lr;
      qa[it] = *(const bf16x8*)(ldwA + hl * 8192 + i * 128 + ((ks * 64 + lg * 16) ^ swz(i, hl)));
    }
    __builtin_amdgcn_s_setprio(1);
    #pragma unroll
    for (int it = 0; it < 2; ++it)
      #pragma unroll
      for (int jt = 0; jt < 4; ++jt)
        sA[it][jt] = __builtin_amdgcn_mfma_f32_16x16x32_bf16(kb[jt], qa[it], sA[it][jt], 0, 0, 0);
    __builtin_amdgcn_s_setprio(0);
  }

  // (3) consume QK(B) batch -> LDS win 2,3
  #pragma unroll
  for (int t = 0; t < 8; ++t) {
    int nt = wv + 8 * t;
    const bool isQ = (t < 4);
    int i  = (lr & 7) * 8 + ((nt >> 2) & 7);
    int h2 = lr >> 3;
    int d0 = (nt & 3) * 16 + lg * 4;
    int off = (isQ ? 0 : 16384) + h2 * 8192 + i * 128 + ((d0 * 2) ^ swz(i, h2));
    #pragma unroll
    for (int win = 2; win < 4; ++win) {
      f32x4 acc = {0.f, 0.f, 0.f, 0.f};
      acc = __builtin_amdgcn_mfma_f32_16x16x32_bf16(qkw[t][0], xa[win][0], acc, 0, 0, 0);
      acc = __builtin_amdgcn_mfma_f32_16x16x32_bf16(qkw[t][1], xa[win][1], acc, 0, 0, 0);
      s16x4 pk;
      #pragma unroll
      for (int r = 0; r < 4; ++r) pk[r] = f2bf(acc[r]);
      *(s16x4*)(lds + win * 32768 + off) = pk;
    }
  }

  // (4) issue V(B) weight batch; softmax(A)+P-store(A) runs while in flight
  bf16x8 vw[4][2];
  #pragma unroll
  for (int u = 0; u < 4; ++u) {
    int ntile = (aq * 4 + u) * 4 + bq;
    int nload = (64 + ntile) * 16 + lr;
    vw[u][0] = *(const bf16x8*)(ws + WCATT_E + nload * 64 + lg * 8);
    vw[u][1] = *(const bf16x8*)(ws + WCATT_E + nload * 64 + 32 + lg * 8);
  }
  #pragma unroll
  for (int it = 0; it < 2; ++it) {
    int i = (ih * 2 + it) * 16 + lr;
    float sum = 0.f;
    #pragma unroll
    for (int jt = 0; jt < 4; ++jt)
      #pragma unroll
      for (int r = 0; r < 4; ++r) {
        float pv = __expf(sA[it][jt][r] + bf2f(posr[it][jt][r]));
        sA[it][jt][r] = pv;
        sum += pv;
      }
    sum += __shfl_xor(sum, 16);
    sum += __shfl_xor(sum, 32);
    float rinv = 1.f / sum;
    #pragma unroll
    for (int jt = 0; jt < 4; ++jt) {
      s16x4 pk;
      #pragma unroll
      for (int r = 0; r < 4; ++r) pk[r] = f2bf(sA[it][jt][r] * rinv);
      *(s16x4*)(ldwA + hl * 8192 + i * 128 + ((jt * 32 + lg * 8) ^ swz(i, hl))) = pk;
    }
  }
  // (5) consume V(B) -> vaccB
  f32x4 vaccB[2][4];
  #pragma unroll
  for (int u = 0; u < 4; ++u)
    #pragma unroll
    for (int win = 2; win < 4; ++win) {
      f32x4 acc = {0.f, 0.f, 0.f, 0.f};
      acc = __builtin_amdgcn_mfma_f32_16x16x32_bf16(xa[win][0], vw[u][0], acc, 0, 0, 0);
      acc = __builtin_amdgcn_mfma_f32_16x16x32_bf16(xa[win][1], vw[u][1], acc, 0, 0, 0);
      vaccB[win - 2][u] = acc;
    }
  __syncthreads();                      // bar2: K(A) reads done; QK(B) in LDS

  // ======== Seg3: V^T(A) stores + attn(B) ========
  {
    int d = bq * 16 + lr;
    #pragma unroll
    for (int win = 0; win < 2; ++win)
      #pragma unroll
      for (int r = 0; r < 4; ++r) {
        int tl = lg * 4 + r;
        int h2 = tl >> 3;
        int jb = (tl & 7) * 16 + aq * 8;
        s16x4 pk;
        #pragma unroll
        for (int u = 0; u < 4; ++u) pk[u] = f2bf(vaccA[win][u][r]);
        *(s16x4*)(lds + win * 32768 + 16384 + h2 * 8192 + d * 128 + (jb ^ swz(d, h2))) = pk;
      }
  }
  char* ldwB = lds + (aw + 2) * 32768;
  f32x4 sB[2][4];
  #pragma unroll
  for (int it = 0; it < 2; ++it)
    #pragma unroll
    for (int jt = 0; jt < 4; ++jt) sB[it][jt] = (f32x4){0.f, 0.f, 0.f, 0.f};
  #pragma unroll
  for (int ks = 0; ks < 2; ++ks) {
    bf16x8 kb[4], qa[2];
    #pragma unroll
    for (int jt = 0; jt < 4; ++jt) {
      int j = jt * 16 + lr;
      kb[jt] = *(const bf16x8*)(ldwB + 16384 + hl * 8192 + j * 128 + ((ks * 64 + lg * 16) ^ swz(j, hl)));
    }
    #pragma unroll
    for (int it = 0; it < 2; ++it) {
      int i = (ih * 2 + it) * 16 + lr;
      qa[it] = *(const bf16x8*)(ldwB + hl * 8192 + i * 128 + ((ks * 64 + lg * 16) ^ swz(i, hl)));
    }
    __builtin_amdgcn_s_setprio(1);
    #pragma unroll
    for (int it = 0; it < 2; ++it)
      #pragma unroll
      for (int jt = 0; jt < 4; ++jt)
        sB[it][jt] = __builtin_amdgcn_mfma_f32_16x16x32_bf16(kb[jt], qa[it], sB[it][jt], 0, 0, 0);
    __builtin_amdgcn_s_setprio(0);
  }
  #pragma unroll
  for (int it = 0; it < 2; ++it) {
    int i = (ih * 2 + it) * 16 + lr;
    float sum = 0.f;
    #pragma unroll
    for (int jt = 0; jt < 4; ++jt)
      #pragma unroll
      for (int r = 0; r < 4; ++r) {
        float pv = __expf(sB[it][jt][r] + bf2f(posr[it][jt][r]));
        sB[it][jt][r] = pv;
        sum += pv;
      }
    sum += __shfl_xor(sum, 16);
    sum += __shfl_xor(sum, 32);
    float rinv = 1.f / sum;
    #pragma unroll
    for (int jt = 0; jt < 4; ++jt) {
      s16x4 pk;
      #pragma unroll
      for (int r = 0; r < 4; ++r) pk[r] = f2bf(sB[it][jt][r] * rinv);
      *(s16x4*)(ldwB + hl * 8192 + i * 128 + ((jt * 32 + lg * 8) ^ swz(i, hl))) = pk;
    }
  }
  __syncthreads();                      // bar3: V^T(A) ready; K(B) reads done

  // ======== Seg4: wofr loads + PV(A)+OH(A) + V^T(B) stores ========
  bf16x8 wofr[16];
  #pragma unroll
  for (int ks = 0; ks < 16; ++ks)
    wofr[ks] = *(const bf16x8*)(ws + WOT_E + (bq * 16 + lr) * 512 + ks * 32 + lg * 8);

  {
    f32x4 o[2][4];
    #pragma unroll
    for (int it = 0; it < 2; ++it)
      #pragma unroll
      for (int dt = 0; dt < 4; ++dt) o[it][dt] = (f32x4){0.f, 0.f, 0.f, 0.f};
    #pragma unroll
    for (int ks = 0; ks < 2; ++ks) {
      bf16x8 vb[4], pa[2];
      #pragma unroll
      for (int dt = 0; dt < 4; ++dt) {
        int d = dt * 16 + lr;
        vb[dt] = *(const bf16x8*)(ldwA + 16384 + hl * 8192 + d * 128 + ((ks * 64 + lg * 16) ^ swz(d, hl)));
      }
      #pragma unroll
      for (int it = 0; it < 2; ++it) {
        int i = (ih * 2 + it) * 16 + lr;
        pa[it] = *(const bf16x8*)(ldwA + hl * 8192 + i * 128 + ((ks * 64 + lg * 16) ^ swz(i, hl)));
      }
      __builtin_amdgcn_s_setprio(1);
      #pragma unroll
      for (int it = 0; it < 2; ++it)
        #pragma unroll
        for (int dt = 0; dt < 4; ++dt)
          o[it][dt] = __builtin_amdgcn_mfma_f32_16x16x32_bf16(vb[dt], pa[it], o[it][dt], 0, 0, 0);
      __builtin_amdgcn_s_setprio(0);
    }
    #pragma unroll
    for (int it = 0; it < 2; ++it) {
      int i  = (ih * 2 + it) * 16 + lr;
      int lm = 8 * hl + (i >> 3);
      int rp = lm * 8 + (i & 7);
      #pragma unroll
      for (int dt = 0; dt < 4; ++dt) {
        s16x4 pk;
        #pragma unroll
        for (int r = 0; r < 4; ++r) pk[r] = f2bf(o[it][dt][r]);
        *(s16x4*)(ldwA + rp * 128 + ((dt * 32 + lg * 8) ^ swz(rp, 0))) = pk;
      }
    }
  }
  {
    int d = bq * 16 + lr;
    #pragma unroll
    for (int win = 2; win < 4; ++win)
      #pragma unroll
      for (int r = 0; r < 4; ++r) {
        int tl = lg * 4 + r;
        int h2 = tl >> 3;
        int jb = (tl & 7) * 16 + aq * 8;
        s16x4 pk;
        #pragma unroll
        for (int u = 0; u < 4; ++u) pk[u] = f2bf(vaccB[win - 2][u][r]);
        *(s16x4*)(lds + win * 32768 + 16384 + h2 * 8192 + d * 128 + (jb ^ swz(d, h2))) = pk;
      }
  }
  __syncthreads();                      // bar4: OH(A) ready; V^T(B) ready

  // ======== Seg5: Wo(A) + PV(B)+OH(B) ========
  {
    f32x4 oacc = {0.f, 0.f, 0.f, 0.f};
    #pragma unroll
    for (int ks = 0; ks < 16; ++ks) {
      int rp = lr * 8 + (ks >> 1);
      int boff = rp * 128 + (((ks & 1) * 64 + lg * 16) ^ swz(rp, 0));
      bf16x8 bA = *(const bf16x8*)(lds + aw * 32768 + boff);
      oacc = __builtin_amdgcn_mfma_f32_16x16x32_bf16(wofr[ks], bA, oacc, 0, 0, 0);
    }
    int c0 = bq * 16 + lg * 4;
    float4 bo4 = *(const float4*)(bo + c0);
    int w   = 4 * q + aw;
    int bb  = w / 576;
    int rem = (w % 576) * 64;
    int hh  = rem / 192;
    int ww0 = rem % 192;
    int src_h = (hh + 4) % 192;
    float* orow = out + (size_t)(bb * 192 + src_h) * 12288;
    int tok = 16 * hp + lr;
    int sw = ww0 + tok + 4; if (sw >= 192) sw -= 192;
    float4 ov;
    ov.x = oacc[0] + bo4.x; ov.y = oacc[1] + bo4.y;
    ov.z = oacc[2] + bo4.z; ov.w = oacc[3] + bo4.w;
    *(float4*)(orow + sw * 64 + c0) = ov;
  }
  {
    f32x4 o[2][4];
    #pragma unroll
    for (int it = 0; it < 2; ++it)
      #pragma unroll
      for (int dt = 0; dt < 4; ++dt) o[it][dt] = (f32x4){0.f, 0.f, 0.f, 0.f};
    #pragma unroll
    for (int ks = 0; ks < 2; ++ks) {
      bf16x8 vb[4], pa[2];
      #pragma unroll
      for (int dt = 0; dt < 4; ++dt) {
        int d = dt * 16 + lr;
        vb[dt] = *(const bf16x8*)(ldwB + 16384 + hl * 8192 + d * 128 + ((ks * 64 + lg * 16) ^ swz(d, hl)));
      }
      #pragma unroll
      for (int it = 0; it < 2; ++it) {
        int i = (ih * 2 + it) * 16 + lr;
        pa[it] = *(const bf16x8*)(ldwB + hl * 8192 + i * 128 + ((ks * 64 + lg * 16) ^ swz(i, hl)));
      }
      __builtin_amdgcn_s_setprio(1);
      #pragma unroll
      for (int it = 0; it < 2; ++it)
        #pragma unroll
        for (int dt = 0; dt < 4; ++dt)
          o[it][dt] = __builtin_amdgcn_mfma_f32_16x16x32_bf16(vb[dt], pa[it], o[it][dt], 0, 0, 0);
      __builtin_amdgcn_s_setprio(0);
    }
    #pragma unroll
    for (int it = 0; it < 2; ++it) {
      int i  = (ih * 2 + it) * 16 + lr;
      int lm = 8 * hl + (i >> 3);
      int rp = lm * 8 + (i & 7);
      #pragma unroll
      for (int dt = 0; dt < 4; ++dt) {
        s16x4 pk;
        #pragma unroll
        for (int r = 0; r < 4; ++r) pk[r] = f2bf(o[it][dt][r]);
        *(s16x4*)(ldwB + rp * 128 + ((dt * 32 + lg * 8) ^ swz(rp, 0))) = pk;
      }
    }
  }
  __syncthreads();                      // bar5: OH(B) ready

  // ======== Seg6: Wo(B) ========
  {
    f32x4 oacc = {0.f, 0.f, 0.f, 0.f};
    #pragma unroll
    for (int ks = 0; ks < 16; ++ks) {
      int rp = lr * 8 + (ks >> 1);
      int boff = rp * 128 + (((ks & 1) * 64 + lg * 16) ^ swz(rp, 0));
      bf16x8 bB = *(const bf16x8*)(lds + (aw + 2) * 32768 + boff);
      oacc = __builtin_amdgcn_mfma_f32_16x16x32_bf16(wofr[ks], bB, oacc, 0, 0, 0);
    }
    int c0 = bq * 16 + lg * 4;
    float4 bo4 = *(const float4*)(bo + c0);
    int w   = 4 * q + aw + 2;
    int bb  = w / 576;
    int rem = (w % 576) * 64;
    int hh  = rem / 192;
    int ww0 = rem % 192;
    int src_h = (hh + 4) % 192;
    float* orow = out + (size_t)(bb * 192 + src_h) * 12288;
    int tok = 16 * hp + lr;
    int sw = ww0 + tok + 4; if (sw >= 192) sw -= 192;
    float4 ov;
    ov.x = oacc[0] + bo4.x; ov.y = oacc[1] + bo4.y;
    ov.z = oacc[2] + bo4.z; ov.w = oacc[3] + bo4.w;
    *(float4*)(orow + sw * 64 + c0) = ov;
  }
}

// ======== G=2 static-LDS kernel (round-11 verified) — fallback ========
__global__ __launch_bounds__(THREADS, 2)
void wmsa_mfma(const float* __restrict__ x, const float* __restrict__ bo,
               const short* __restrict__ ws, float* __restrict__ out) {
  __shared__ __align__(16) char lds[65536];
  const int tid = threadIdx.x;
  const int wv = tid >> 6;
  const int l  = tid & 63;
  const int lr = l & 15;
  const int lg = l >> 4;

  const int bid = blockIdx.x;
  const int p   = bid >> 2;
  const int hp  = bid & 3;

  const float* xrow[2];
  float* orow[2];
  int ww0a[2];
  #pragma unroll
  for (int win = 0; win < 2; ++win) {
    int w   = 2 * p + win;
    int t0  = w * 64;
    int bb  = t0 / 36864;
    int rem = t0 % 36864;
    int hh  = rem / 192;
    ww0a[win] = rem % 192;
    int src_h = (hh + 4) % 192;
    xrow[win] = x + (size_t)(bb * 192 + src_h) * 12288;
    orow[win] = out + (size_t)(bb * 192 + src_h) * 12288;
  }

  bf16x8 xa[2][2];
  #pragma unroll
  for (int win = 0; win < 2; ++win) {
    int tok = 16 * hp + lr;
    int sw = ww0a[win] + tok + 4; if (sw >= 192) sw -= 192;
    const float* xp = xrow[win] + sw * 64;
    #pragma unroll
    for (int ks = 0; ks < 2; ++ks) {
      float4 a = *(const float4*)(xp + ks * 32 + lg * 8);
      float4 b = *(const float4*)(xp + ks * 32 + lg * 8 + 4);
      bf16x8 v;
      v[0] = f2bf(a.x); v[1] = f2bf(a.y); v[2] = f2bf(a.z); v[3] = f2bf(a.w);
      v[4] = f2bf(b.x); v[5] = f2bf(b.y); v[6] = f2bf(b.z); v[7] = f2bf(b.w);
      xa[win][ks] = v;
    }
  }

  #pragma unroll 4
  for (int t = 0; t < 16; ++t) {
    int nt = wv + 4 * t;
    int nload = nt * 16 + lr;
    bf16x8 b0 = *(const bf16x8*)(ws + WCATT_E + nload * 64 + lg * 8);
    bf16x8 b1 = *(const bf16x8*)(ws + WCATT_E + nload * 64 + 32 + lg * 8);
    const bool isQ = (t < 8);
    int i  = (lr & 7) * 8 + (t & 7);
    int h2 = lr >> 3;
    int d0 = wv * 16 + lg * 4;
    int off = (isQ ? 0 : 16384) + h2 * 8192 + i * 128 + ((d0 * 2) ^ swz(i, h2));
    #pragma unroll
    for (int win = 0; win < 2; ++win) {
      f32x4 acc = {0.f, 0.f, 0.f, 0.f};
      acc = __builtin_amdgcn_mfma_f32_16x16x32_bf16(b0, xa[win][0], acc, 0, 0, 0);
      acc = __builtin_amdgcn_mfma_f32_16x16x32_bf16(b1, xa[win][1], acc, 0, 0, 0);
      s16x4 pk;
      #pragma unroll
      for (int r = 0; r < 4; ++r) pk[r] = f2bf(acc[r]);
      *(s16x4*)(lds + win * 32768 + off) = pk;
    }
  }

  f32x4 vacc[2][8];
  #pragma unroll
  for (int tv = 0; tv < 8; ++tv) {
    int nload = (64 + wv + 4 * tv) * 16 + lr;
    bf16x8 b0 = *(const bf16x8*)(ws + WCATT_E + nload * 64 + lg * 8);
    bf16x8 b1 = *(const bf16x8*)(ws + WCATT_E + nload * 64 + 32 + lg * 8);
    #pragma unroll
    for (int win = 0; win < 2; ++win) {
      f32x4 acc = {0.f, 0.f, 0.f, 0.f};
      acc = __builtin_amdgcn_mfma_f32_16x16x32_bf16(xa[win][0], b0, acc, 0, 0, 0);
      acc = __builtin_amdgcn_mfma_f32_16x16x32_bf16(xa[win][1], b1, acc, 0, 0, 0);
      vacc[win][tv] = acc;
    }
  }
  __syncthreads();

  const int hl = wv >> 1;
  const int ih = wv & 1;
  const int hglob = 2 * hp + hl;

  s16x4 posr[2][4];
  #pragma unroll
  for (int it = 0; it < 2; ++it) {
    int i = (ih * 2 + it) * 16 + lr;
    const short* pp = ws + POS_E + hglob * 4096 + i * 64;
    #pragma unroll
    for (int jt = 0; jt < 4; ++jt)
      posr[it][jt] = *(const s16x4*)(pp + jt * 16 + lg * 4);
  }

  #pragma unroll
  for (int win = 0; win < 2; ++win) {
    char* ldw = lds + win * 32768;
    f32x4 s[2][4];
    #pragma unroll
    for (int it = 0; it < 2; ++it)
      #pragma unroll
      for (int jt = 0; jt < 4; ++jt) s[it][jt] = (f32x4){0.f, 0.f, 0.f, 0.f};

    #pragma unroll
    for (int ks = 0; ks < 2; ++ks) {
      bf16x8 kb[4], qa[2];
      #pragma unroll
      for (int jt = 0; jt < 4; ++jt) {
        int j = jt * 16 + lr;
        kb[jt] = *(const bf16x8*)(ldw + 16384 + hl * 8192 + j * 128 + ((ks * 64 + lg * 16) ^ swz(j, hl)));
      }
      #pragma unroll
      for (int it = 0; it < 2; ++it) {
        int i = (ih * 2 + it) * 16 + lr;
        qa[it] = *(const bf16x8*)(ldw + hl * 8192 + i * 128 + ((ks * 64 + lg * 16) ^ swz(i, hl)));
      }
      __builtin_amdgcn_s_setprio(1);
      #pragma unroll
      for (int it = 0; it < 2; ++it)
        #pragma unroll
        for (int jt = 0; jt < 4; ++jt)
          s[it][jt] = __builtin_amdgcn_mfma_f32_16x16x32_bf16(kb[jt], qa[it], s[it][jt], 0, 0, 0);
      __builtin_amdgcn_s_setprio(0);
    }

    #pragma unroll
    for (int it = 0; it < 2; ++it) {
      int i = (ih * 2 + it) * 16 + lr;
      float sum = 0.f;
      #pragma unroll
      for (int jt = 0; jt < 4; ++jt)
        #pragma unroll
        for (int r = 0; r < 4; ++r) {
          float pv = __expf(s[it][jt][r] + bf2f(posr[it][jt][r]));
          s[it][jt][r] = pv;
          sum += pv;
        }
      sum += __shfl_xor(sum, 16);
      sum += __shfl_xor(sum, 32);
      float rinv = 1.f / sum;
      #pragma unroll
      for (int jt = 0; jt < 4; ++jt) {
        s16x4 pk;
        #pragma unroll
        for (int r = 0; r < 4; ++r) pk[r] = f2bf(s[it][jt][r] * rinv);
        *(s16x4*)(ldw + hl * 8192 + i * 128 + ((jt * 32 + lg * 8) ^ swz(i, hl))) = pk;
      }
    }
  }
  __syncthreads();

  {
    int d = wv * 16 + lr;
    #pragma unroll
    for (int win = 0; win < 2; ++win)
      #pragma unroll
      for (int r = 0; r < 4; ++r) {
        int tl = lg * 4 + r;
        int h2 = tl >> 3;
        int slot = tl & 7;
        bf16x8 pk;
        #pragma unroll
        for (int tv = 0; tv < 8; ++tv) pk[tv] = f2bf(vacc[win][tv][r]);
        *(bf16x8*)(lds + win * 32768 + 16384 + h2 * 8192 + d * 128 + ((slot * 16) ^ swz(d, h2))) = pk;
      }
  }
  __syncthreads();

  bf16x8 wofr[16];
  #pragma unroll
  for (int ks = 0; ks < 16; ++ks)
    wofr[ks] = *(const bf16x8*)(ws + WOT_E + (wv * 16 + lr) * 512 + ks * 32 + lg * 8);

  #pragma unroll
  for (int win = 0; win < 2; ++win) {
    char* ldw = lds + win * 32768;
    f32x4 o[2][4];
    #pragma unroll
    for (int it = 0; it < 2; ++it)
      #pragma unroll
      for (int dt = 0; dt < 4; ++dt) o[it][dt] = (f32x4){0.f, 0.f, 0.f, 0.f};
    #pragma unroll
    for (int ks = 0; ks < 2; ++ks) {
      bf16x8 vb[4], pa[2];
      #pragma unroll
      for (int dt = 0; dt < 4; ++dt) {
        int d = dt * 16 + lr;
        vb[dt] = *(const bf16x8*)(ldw + 16384 + hl * 8192 + d * 128 + ((ks * 64 + lg * 16) ^ swz(d, hl)));
      }
      #pragma unroll
      for (int it = 0; it < 2; ++it) {
        int i = (ih * 2 + it) * 16 + lr;
        pa[it] = *(const bf16x8*)(ldw + hl * 8192 + i * 128 + ((ks * 64 + lg * 16) ^ swz(i, hl)));
      }
      __builtin_amdgcn_s_setprio(1);
      #pragma unroll
      for (int it = 0; it < 2; ++it)
        #pragma unroll
        for (int dt = 0; dt < 4; ++dt)
          o[it][dt] = __builtin_amdgcn_mfma_f32_16x16x32_bf16(vb[dt], pa[it], o[it][dt], 0, 0, 0);
      __builtin_amdgcn_s_setprio(0);
    }
    #pragma unroll
    for (int it = 0; it < 2; ++it) {
      int i  = (ih * 2 + it) * 16 + lr;
      int lm = 8 * hl + (i >> 3);
      int rp = lm * 8 + (i & 7);
      #pragma unroll
      for (int dt = 0; dt < 4; ++dt) {
        s16x4 pk;
        #pragma unroll
        for (int r = 0; r < 4; ++r) pk[r] = f2bf(o[it][dt][r]);
        *(s16x4*)(ldw + rp * 128 + ((dt * 32 + lg * 8) ^ swz(rp, 0))) = pk;
      }
    }
  }
  __syncthreads();

  f32x4 oacc[2];
  oacc[0] = (f32x4){0.f, 0.f, 0.f, 0.f};
  oacc[1] = (f32x4){0.f, 0.f, 0.f, 0.f};
  #pragma unroll
  for (int ks = 0; ks < 16; ++ks) {
    int rp = lr * 8 + (ks >> 1);
    int boff = rp * 128 + (((ks & 1) * 64 + lg * 16) ^ swz(rp, 0));
    #pragma unroll
    for (int win = 0; win < 2; ++win) {
      bf16x8 bfrOH = *(const bf16x8*)(lds + win * 32768 + boff);
      oacc[win] = __builtin_amdgcn_mfma_f32_16x16x32_bf16(wofr[ks], bfrOH, oacc[win], 0, 0, 0);
    }
  }
  {
    int c0 = wv * 16 + lg * 4;
    float4 bo4 = *(const float4*)(bo + c0);
    int tok = 16 * hp + lr;
    #pragma unroll
    for (int win = 0; win < 2; ++win) {
      int sw = ww0a[win] + tok + 4; if (sw >= 192) sw -= 192;
      float4 ov;
      ov.x = oacc[win][0] + bo4.x; ov.y = oacc[win][1] + bo4.y;
      ov.z = oacc[win][2] + bo4.z; ov.w = oacc[win][3] + bo4.w;
      *(float4*)(orow[win] + sw * 64 + c0) = ov;
    }
  }
}

extern "C" void kernel_launch(void* const* d_in, const int* in_sizes, int n_in,
                              void* d_out, int out_size, void* d_ws, size_t ws_size,
                              hipStream_t stream) {
  const float* x    = (const float*)d_in[0];
  const float* Wq   = (const float*)d_in[1];
  const float* Wkv  = (const float*)d_in[2];
  const float* Wo   = (const float*)d_in[3];
  const float* bo   = (const float*)d_in[4];
  const float* pos  = (const float*)d_in[5];
  float* o = (float*)d_out;
  wmsa_prep<<<dim3(640), dim3(256), 0, stream>>>(Wq, Wkv, Wo, pos, (short*)d_ws);
  hipError_t e = hipFuncSetAttribute((const void*)wmsa_pipe,
                                     hipFuncAttributeMaxDynamicSharedMemorySize, 131072);
  if (e == hipSuccess) {
    wmsa_pipe<<<dim3(NWIN), dim3(512), 131072, stream>>>(x, bo, (const short*)d_ws, o);
  } else {
    wmsa_mfma<<<dim3(NWIN * 2), dim3(THREADS), 0, stream>>>(x, bo, (const short*)d_ws, o);
  }
}

// Round 18
// 175.277 us; speedup vs baseline: 1.3034x; 1.3034x over previous
//
#include <hip/hip_runtime.h>
#include <hip/hip_bf16.h>
#include <stdint.h>

typedef __attribute__((ext_vector_type(8))) short bf16x8;   // 8 bf16 = 4 VGPRs
typedef __attribute__((ext_vector_type(4))) short s16x4;    // 4 bf16 = 8 B
typedef __attribute__((ext_vector_type(4))) float f32x4;

#define THREADS 256
constexpr int NWIN = 2304;

// d_ws layout (bf16 element offsets)
constexpr int WCATT_E = 0;        // [1536][64]  : col n of [Wq*0.125|Wkv_k|Wkv_v], 64 k contiguous
constexpr int WOT_E   = 98304;    // [64][512]   : col n of Wo, 512 k contiguous
constexpr int POS_E   = 131072;   // [8][64][64]
constexpr size_t WS_NEED = 327680; // bytes

// Compiler-generated cast (emits v_cvt_pk_bf16_f32 pairs; T12/m240: scalar
// cast beats hand-written conversion). RNE.
__device__ __forceinline__ short f2bf(float f) {
  __hip_bfloat16 h = __float2bfloat16(f);
  return __builtin_bit_cast(short, h);
}
__device__ __forceinline__ float bf2f(short s) {
  uint32_t u = ((uint32_t)(uint16_t)s) << 16;
  return __builtin_bit_cast(float, u);
}
// 16B-slot XOR key; same involution on write and read sides.
__device__ __forceinline__ int swz(int row, int h) {
  return ((((row ^ (row >> 2) ^ (row >> 3)) & 7) ^ h) << 4);
}

// ---------------- prep: weights -> bf16 transposed in ws ----------------
__global__ void wmsa_prep(const float* __restrict__ Wq, const float* __restrict__ Wkv,
                          const float* __restrict__ Wo, const float* __restrict__ pos,
                          short* __restrict__ ws) {
  int idx = blockIdx.x * 256 + threadIdx.x;
  if (idx < 32768) {                       // Wq -> WcatT[n][k], pre-scaled by 0.125
    int n = idx & 511, k = idx >> 9;
    ws[WCATT_E + n * 64 + k] = f2bf(Wq[k * 512 + n] * 0.125f);
  } else if (idx < 98304) {                // Wkv -> WcatT[512+nkv][k]
    int j = idx - 32768;
    int nkv = j & 1023, k = j >> 10;
    ws[WCATT_E + (512 + nkv) * 64 + k] = f2bf(Wkv[k * 1024 + nkv]);
  } else if (idx < 131072) {               // Wo -> WoT[n][k]
    int j = idx - 98304;
    int n = j & 63, k = j >> 6;
    ws[WOT_E + n * 512 + k] = f2bf(Wo[k * 64 + n]);
  } else if (idx < 163840) {               // pos -> bf16 (natural [h][i][j])
    int j = idx - 131072;
    ws[POS_E + j] = f2bf(pos[j]);
  }
}

// ======== G=4 kernel (round-16 verified best, 175.95us) ========
// One 512-thread block per (window-QUAD, head-pair); 4 windows share every
// weight-fragment load. 128 KB dynamic LDS (1 block/CU, 8 waves = 2/SIMD).
// LDS: win*32768 + { QP [0,16K) (Q->P->OH), KV [16K,32K) } per window.
// MFMA convention: mfma(A,B,C): C[m][n] = sum_k A[m,k]B[n,k];
//   A row = l&15, B row = l&15, C: n = lane&15, m = (lane>>4)*4 + r.
__global__ __launch_bounds__(512, 2)
void wmsa_mfma4(const float* __restrict__ x, const float* __restrict__ bo,
                const short* __restrict__ ws, float* __restrict__ out) {
  extern __shared__ __align__(16) char lds[];
  const int tid = threadIdx.x;
  const int wv = tid >> 6;       // 0..7
  const int l  = tid & 63;
  const int lr = l & 15;
  const int lg = l >> 4;

  const int bid = blockIdx.x;
  const int q   = bid >> 2;          // window quad 0..575
  const int hp  = bid & 3;           // head-pair

  // ---- X fragments for all 4 windows ----
  bf16x8 xa[4][2];
  #pragma unroll
  for (int win = 0; win < 4; ++win) {
    int w   = 4 * q + win;
    int bb  = w / 576;
    int rem = (w % 576) * 64;
    int hh  = rem / 192;
    int ww0 = rem % 192;
    int src_h = (hh + 4) % 192;
    const float* xp = x + (size_t)(bb * 192 + src_h) * 12288;
    int tok = 16 * hp + lr;
    int sw = ww0 + tok + 4; if (sw >= 192) sw -= 192;
    const float* xq = xp + sw * 64;
    #pragma unroll
    for (int ks = 0; ks < 2; ++ks) {
      float4 a = *(const float4*)(xq + ks * 32 + lg * 8);
      float4 b = *(const float4*)(xq + ks * 32 + lg * 8 + 4);
      bf16x8 v;
      v[0] = f2bf(a.x); v[1] = f2bf(a.y); v[2] = f2bf(a.z); v[3] = f2bf(a.w);
      v[4] = f2bf(b.x); v[5] = f2bf(b.y); v[6] = f2bf(b.z); v[7] = f2bf(b.w);
      xa[win][ks] = v;
    }
  }

  // ---- Phase 1: QK-GEMM (A=Wcat, B=X); nt = wv + 8t ----
  #pragma unroll
  for (int t = 0; t < 8; ++t) {
    int nt = wv + 8 * t;
    int nload = nt * 16 + lr;
    bf16x8 b0 = *(const bf16x8*)(ws + WCATT_E + nload * 64 + lg * 8);
    bf16x8 b1 = *(const bf16x8*)(ws + WCATT_E + nload * 64 + 32 + lg * 8);
    const bool isQ = (t < 4);
    int i  = (lr & 7) * 8 + ((nt >> 2) & 7);
    int h2 = lr >> 3;
    int d0 = (nt & 3) * 16 + lg * 4;     // nt&3 == wv&3
    int off = (isQ ? 0 : 16384) + h2 * 8192 + i * 128 + ((d0 * 2) ^ swz(i, h2));
    #pragma unroll
    for (int win = 0; win < 4; ++win) {
      f32x4 acc = {0.f, 0.f, 0.f, 0.f};
      acc = __builtin_amdgcn_mfma_f32_16x16x32_bf16(b0, xa[win][0], acc, 0, 0, 0);
      acc = __builtin_amdgcn_mfma_f32_16x16x32_bf16(b1, xa[win][1], acc, 0, 0, 0);
      s16x4 pk;
      #pragma unroll
      for (int r = 0; r < 4; ++r) pk[r] = f2bf(acc[r]);
      *(s16x4*)(lds + win * 32768 + off) = pk;
    }
  }

  // ---- Phase 2a (pre-bar1, reg-only): V-GEMM; wave owns d-quad bq, j-quad aq ----
  const int bq = wv & 3, aq = wv >> 2;
  f32x4 vacc[4][4];
  #pragma unroll
  for (int u = 0; u < 4; ++u) {
    int ntile = (aq * 4 + u) * 4 + bq;
    int nload = (64 + ntile) * 16 + lr;
    bf16x8 b0 = *(const bf16x8*)(ws + WCATT_E + nload * 64 + lg * 8);
    bf16x8 b1 = *(const bf16x8*)(ws + WCATT_E + nload * 64 + 32 + lg * 8);
    #pragma unroll
    for (int win = 0; win < 4; ++win) {
      f32x4 acc = {0.f, 0.f, 0.f, 0.f};
      acc = __builtin_amdgcn_mfma_f32_16x16x32_bf16(xa[win][0], b0, acc, 0, 0, 0);
      acc = __builtin_amdgcn_mfma_f32_16x16x32_bf16(xa[win][1], b1, acc, 0, 0, 0);
      vacc[win][u] = acc;
    }
  }
  __syncthreads();                      // bar1: Q,K complete (all 4 windows)

  const int hl = (wv >> 1) & 1;
  const int ih = wv & 1;
  const int hglob = 2 * hp + hl;
  const int wbase = aq;                 // wave handles windows {wbase, wbase+2}

  // pos fragments for this wave's (head, i-half)
  s16x4 posr[2][4];
  #pragma unroll
  for (int it = 0; it < 2; ++it) {
    int i = (ih * 2 + it) * 16 + lr;
    const short* pp = ws + POS_E + hglob * 4096 + i * 64;
    #pragma unroll
    for (int jt = 0; jt < 4; ++jt)
      posr[it][jt] = *(const s16x4*)(pp + jt * 16 + lg * 4);
  }

  // ---- Phase 2b: QK^T + softmax + P-store for windows {wbase, wbase+2} ----
  #pragma unroll
  for (int c = 0; c < 2; ++c) {
    char* ldw = lds + (wbase + 2 * c) * 32768;
    f32x4 s[2][4];
    #pragma unroll
    for (int it = 0; it < 2; ++it)
      #pragma unroll
      for (int jt = 0; jt < 4; ++jt) s[it][jt] = (f32x4){0.f, 0.f, 0.f, 0.f};

    #pragma unroll
    for (int ks = 0; ks < 2; ++ks) {
      bf16x8 kb[4], qa[2];
      #pragma unroll
      for (int jt = 0; jt < 4; ++jt) {
        int j = jt * 16 + lr;
        kb[jt] = *(const bf16x8*)(ldw + 16384 + hl * 8192 + j * 128 + ((ks * 64 + lg * 16) ^ swz(j, hl)));
      }
      #pragma unroll
      for (int it = 0; it < 2; ++it) {
        int i = (ih * 2 + it) * 16 + lr;
        qa[it] = *(const bf16x8*)(ldw + hl * 8192 + i * 128 + ((ks * 64 + lg * 16) ^ swz(i, hl)));
      }
      __builtin_amdgcn_s_setprio(1);
      #pragma unroll
      for (int it = 0; it < 2; ++it)
        #pragma unroll
        for (int jt = 0; jt < 4; ++jt)
          s[it][jt] = __builtin_amdgcn_mfma_f32_16x16x32_bf16(kb[jt], qa[it], s[it][jt], 0, 0, 0);
      __builtin_amdgcn_s_setprio(0);
    }

    // softmax (row i lane-fixed; no max-subtraction, |sim|<~9 fp32-safe)
    #pragma unroll
    for (int it = 0; it < 2; ++it) {
      int i = (ih * 2 + it) * 16 + lr;
      float sum = 0.f;
      #pragma unroll
      for (int jt = 0; jt < 4; ++jt)
        #pragma unroll
        for (int r = 0; r < 4; ++r) {
          float pv = __expf(s[it][jt][r] + bf2f(posr[it][jt][r]));
          s[it][jt][r] = pv;
          sum += pv;
        }
      sum += __shfl_xor(sum, 16);
      sum += __shfl_xor(sum, 32);
      float rinv = 1.f / sum;
      #pragma unroll
      for (int jt = 0; jt < 4; ++jt) {
        s16x4 pk;
        #pragma unroll
        for (int r = 0; r < 4; ++r) pk[r] = f2bf(s[it][jt][r] * rinv);
        *(s16x4*)(ldw + hl * 8192 + i * 128 + ((jt * 32 + lg * 8) ^ swz(i, hl))) = pk;
      }
    }
  }
  __syncthreads();                      // bar2: K reads done (all windows)

  // ---- Phase 3: V^T stores (8B j-runs; j = (tl&7)*8 + aq*4 + u) ----
  {
    int d = bq * 16 + lr;
    #pragma unroll
    for (int win = 0; win < 4; ++win)
      #pragma unroll
      for (int r = 0; r < 4; ++r) {
        int tl = lg * 4 + r;
        int h2 = tl >> 3;
        int jb = (tl & 7) * 16 + aq * 8;
        s16x4 pk;
        #pragma unroll
        for (int u = 0; u < 4; ++u) pk[u] = f2bf(vacc[win][u][r]);
        *(s16x4*)(lds + win * 32768 + 16384 + h2 * 8192 + d * 128 + (jb ^ swz(d, h2))) = pk;
      }
  }
  __syncthreads();                      // bar3: V^T ready

  // ---- Wo issue-early (short-lived): ct = bq; used for both windows in phase 5 ----
  bf16x8 wofr[16];
  #pragma unroll
  for (int ks = 0; ks < 16; ++ks)
    wofr[ks] = *(const bf16x8*)(ws + WOT_E + (bq * 16 + lr) * 512 + ks * 32 + lg * 8);

  // ---- Phase 4: PV + OH stores for windows {wbase, wbase+2} ----
  #pragma unroll
  for (int c = 0; c < 2; ++c) {
    char* ldw = lds + (wbase + 2 * c) * 32768;
    f32x4 o[2][4];
    #pragma unroll
    for (int it = 0; it < 2; ++it)
      #pragma unroll
      for (int dt = 0; dt < 4; ++dt) o[it][dt] = (f32x4){0.f, 0.f, 0.f, 0.f};
    #pragma unroll
    for (int ks = 0; ks < 2; ++ks) {
      bf16x8 vb[4], pa[2];
      #pragma unroll
      for (int dt = 0; dt < 4; ++dt) {
        int d = dt * 16 + lr;
        vb[dt] = *(const bf16x8*)(ldw + 16384 + hl * 8192 + d * 128 + ((ks * 64 + lg * 16) ^ swz(d, hl)));
      }
      #pragma unroll
      for (int it = 0; it < 2; ++it) {
        int i = (ih * 2 + it) * 16 + lr;
        pa[it] = *(const bf16x8*)(ldw + hl * 8192 + i * 128 + ((ks * 64 + lg * 16) ^ swz(i, hl)));
      }
      __builtin_amdgcn_s_setprio(1);
      #pragma unroll
      for (int it = 0; it < 2; ++it)
        #pragma unroll
        for (int dt = 0; dt < 4; ++dt)
          o[it][dt] = __builtin_amdgcn_mfma_f32_16x16x32_bf16(vb[dt], pa[it], o[it][dt], 0, 0, 0);
      __builtin_amdgcn_s_setprio(0);
    }
    // OH scatter: wave-private rows (this wave's own P byte-range)
    #pragma unroll
    for (int it = 0; it < 2; ++it) {
      int i  = (ih * 2 + it) * 16 + lr;
      int lm = 8 * hl + (i >> 3);
      int rp = lm * 8 + (i & 7);
      #pragma unroll
      for (int dt = 0; dt < 4; ++dt) {
        s16x4 pk;
        #pragma unroll
        for (int r = 0; r < 4; ++r) pk[r] = f2bf(o[it][dt][r]);
        *(s16x4*)(ldw + rp * 128 + ((dt * 32 + lg * 8) ^ swz(rp, 0))) = pk;
      }
    }
  }
  __syncthreads();                      // bar4: OH complete

  // ---- Phase 5: Wo for (ct = bq) x windows {wbase, wbase+2} ----
  f32x4 oacc0 = {0.f, 0.f, 0.f, 0.f};
  f32x4 oacc1 = {0.f, 0.f, 0.f, 0.f};
  #pragma unroll
  for (int ks = 0; ks < 16; ++ks) {
    int rp = lr * 8 + (ks >> 1);
    int boff = rp * 128 + (((ks & 1) * 64 + lg * 16) ^ swz(rp, 0));
    bf16x8 bA = *(const bf16x8*)(lds + wbase * 32768 + boff);
    bf16x8 bB = *(const bf16x8*)(lds + (wbase + 2) * 32768 + boff);
    oacc0 = __builtin_amdgcn_mfma_f32_16x16x32_bf16(wofr[ks], bA, oacc0, 0, 0, 0);
    oacc1 = __builtin_amdgcn_mfma_f32_16x16x32_bf16(wofr[ks], bB, oacc1, 0, 0, 0);
  }
  {
    int c0 = bq * 16 + lg * 4;
    float4 bo4 = *(const float4*)(bo + c0);
    int tok = 16 * hp + lr;
    #pragma unroll
    for (int c = 0; c < 2; ++c) {
      int w   = 4 * q + wbase + 2 * c;
      int bb  = w / 576;
      int rem = (w % 576) * 64;
      int hh  = rem / 192;
      int ww0 = rem % 192;
      int src_h = (hh + 4) % 192;
      float* orow = out + (size_t)(bb * 192 + src_h) * 12288;
      int sw = ww0 + tok + 4; if (sw >= 192) sw -= 192;
      f32x4 oa = c ? oacc1 : oacc0;
      float4 ov;
      ov.x = oa[0] + bo4.x; ov.y = oa[1] + bo4.y;
      ov.z = oa[2] + bo4.z; ov.w = oa[3] + bo4.w;
      *(float4*)(orow + sw * 64 + c0) = ov;
    }
  }
}

// ======== G=2 static-LDS kernel (round-11 verified) — fallback ========
__global__ __launch_bounds__(THREADS, 2)
void wmsa_mfma(const float* __restrict__ x, const float* __restrict__ bo,
               const short* __restrict__ ws, float* __restrict__ out) {
  __shared__ __align__(16) char lds[65536];
  const int tid = threadIdx.x;
  const int wv = tid >> 6;
  const int l  = tid & 63;
  const int lr = l & 15;
  const int lg = l >> 4;

  const int bid = blockIdx.x;
  const int p   = bid >> 2;
  const int hp  = bid & 3;

  const float* xrow[2];
  float* orow[2];
  int ww0a[2];
  #pragma unroll
  for (int win = 0; win < 2; ++win) {
    int w   = 2 * p + win;
    int t0  = w * 64;
    int bb  = t0 / 36864;
    int rem = t0 % 36864;
    int hh  = rem / 192;
    ww0a[win] = rem % 192;
    int src_h = (hh + 4) % 192;
    xrow[win] = x + (size_t)(bb * 192 + src_h) * 12288;
    orow[win] = out + (size_t)(bb * 192 + src_h) * 12288;
  }

  bf16x8 xa[2][2];
  #pragma unroll
  for (int win = 0; win < 2; ++win) {
    int tok = 16 * hp + lr;
    int sw = ww0a[win] + tok + 4; if (sw >= 192) sw -= 192;
    const float* xp = xrow[win] + sw * 64;
    #pragma unroll
    for (int ks = 0; ks < 2; ++ks) {
      float4 a = *(const float4*)(xp + ks * 32 + lg * 8);
      float4 b = *(const float4*)(xp + ks * 32 + lg * 8 + 4);
      bf16x8 v;
      v[0] = f2bf(a.x); v[1] = f2bf(a.y); v[2] = f2bf(a.z); v[3] = f2bf(a.w);
      v[4] = f2bf(b.x); v[5] = f2bf(b.y); v[6] = f2bf(b.z); v[7] = f2bf(b.w);
      xa[win][ks] = v;
    }
  }

  #pragma unroll 4
  for (int t = 0; t < 16; ++t) {
    int nt = wv + 4 * t;
    int nload = nt * 16 + lr;
    bf16x8 b0 = *(const bf16x8*)(ws + WCATT_E + nload * 64 + lg * 8);
    bf16x8 b1 = *(const bf16x8*)(ws + WCATT_E + nload * 64 + 32 + lg * 8);
    const bool isQ = (t < 8);
    int i  = (lr & 7) * 8 + (t & 7);
    int h2 = lr >> 3;
    int d0 = wv * 16 + lg * 4;
    int off = (isQ ? 0 : 16384) + h2 * 8192 + i * 128 + ((d0 * 2) ^ swz(i, h2));
    #pragma unroll
    for (int win = 0; win < 2; ++win) {
      f32x4 acc = {0.f, 0.f, 0.f, 0.f};
      acc = __builtin_amdgcn_mfma_f32_16x16x32_bf16(b0, xa[win][0], acc, 0, 0, 0);
      acc = __builtin_amdgcn_mfma_f32_16x16x32_bf16(b1, xa[win][1], acc, 0, 0, 0);
      s16x4 pk;
      #pragma unroll
      for (int r = 0; r < 4; ++r) pk[r] = f2bf(acc[r]);
      *(s16x4*)(lds + win * 32768 + off) = pk;
    }
  }

  f32x4 vacc[2][8];
  #pragma unroll
  for (int tv = 0; tv < 8; ++tv) {
    int nload = (64 + wv + 4 * tv) * 16 + lr;
    bf16x8 b0 = *(const bf16x8*)(ws + WCATT_E + nload * 64 + lg * 8);
    bf16x8 b1 = *(const bf16x8*)(ws + WCATT_E + nload * 64 + 32 + lg * 8);
    #pragma unroll
    for (int win = 0; win < 2; ++win) {
      f32x4 acc = {0.f, 0.f, 0.f, 0.f};
      acc = __builtin_amdgcn_mfma_f32_16x16x32_bf16(xa[win][0], b0, acc, 0, 0, 0);
      acc = __builtin_amdgcn_mfma_f32_16x16x32_bf16(xa[win][1], b1, acc, 0, 0, 0);
      vacc[win][tv] = acc;
    }
  }
  __syncthreads();

  const int hl = wv >> 1;
  const int ih = wv & 1;
  const int hglob = 2 * hp + hl;

  s16x4 posr[2][4];
  #pragma unroll
  for (int it = 0; it < 2; ++it) {
    int i = (ih * 2 + it) * 16 + lr;
    const short* pp = ws + POS_E + hglob * 4096 + i * 64;
    #pragma unroll
    for (int jt = 0; jt < 4; ++jt)
      posr[it][jt] = *(const s16x4*)(pp + jt * 16 + lg * 4);
  }

  #pragma unroll
  for (int win = 0; win < 2; ++win) {
    char* ldw = lds + win * 32768;
    f32x4 s[2][4];
    #pragma unroll
    for (int it = 0; it < 2; ++it)
      #pragma unroll
      for (int jt = 0; jt < 4; ++jt) s[it][jt] = (f32x4){0.f, 0.f, 0.f, 0.f};

    #pragma unroll
    for (int ks = 0; ks < 2; ++ks) {
      bf16x8 kb[4], qa[2];
      #pragma unroll
      for (int jt = 0; jt < 4; ++jt) {
        int j = jt * 16 + lr;
        kb[jt] = *(const bf16x8*)(ldw + 16384 + hl * 8192 + j * 128 + ((ks * 64 + lg * 16) ^ swz(j, hl)));
      }
      #pragma unroll
      for (int it = 0; it < 2; ++it) {
        int i = (ih * 2 + it) * 16 + lr;
        qa[it] = *(const bf16x8*)(ldw + hl * 8192 + i * 128 + ((ks * 64 + lg * 16) ^ swz(i, hl)));
      }
      __builtin_amdgcn_s_setprio(1);
      #pragma unroll
      for (int it = 0; it < 2; ++it)
        #pragma unroll
        for (int jt = 0; jt < 4; ++jt)
          s[it][jt] = __builtin_amdgcn_mfma_f32_16x16x32_bf16(kb[jt], qa[it], s[it][jt], 0, 0, 0);
      __builtin_amdgcn_s_setprio(0);
    }

    #pragma unroll
    for (int it = 0; it < 2; ++it) {
      int i = (ih * 2 + it) * 16 + lr;
      float sum = 0.f;
      #pragma unroll
      for (int jt = 0; jt < 4; ++jt)
        #pragma unroll
        for (int r = 0; r < 4; ++r) {
          float pv = __expf(s[it][jt][r] + bf2f(posr[it][jt][r]));
          s[it][jt][r] = pv;
          sum += pv;
        }
      sum += __shfl_xor(sum, 16);
      sum += __shfl_xor(sum, 32);
      float rinv = 1.f / sum;
      #pragma unroll
      for (int jt = 0; jt < 4; ++jt) {
        s16x4 pk;
        #pragma unroll
        for (int r = 0; r < 4; ++r) pk[r] = f2bf(s[it][jt][r] * rinv);
        *(s16x4*)(ldw + hl * 8192 + i * 128 + ((jt * 32 + lg * 8) ^ swz(i, hl))) = pk;
      }
    }
  }
  __syncthreads();

  {
    int d = wv * 16 + lr;
    #pragma unroll
    for (int win = 0; win < 2; ++win)
      #pragma unroll
      for (int r = 0; r < 4; ++r) {
        int tl = lg * 4 + r;
        int h2 = tl >> 3;
        int slot = tl & 7;
        bf16x8 pk;
        #pragma unroll
        for (int tv = 0; tv < 8; ++tv) pk[tv] = f2bf(vacc[win][tv][r]);
        *(bf16x8*)(lds + win * 32768 + 16384 + h2 * 8192 + d * 128 + ((slot * 16) ^ swz(d, h2))) = pk;
      }
  }
  __syncthreads();

  bf16x8 wofr[16];
  #pragma unroll
  for (int ks = 0; ks < 16; ++ks)
    wofr[ks] = *(const bf16x8*)(ws + WOT_E + (wv * 16 + lr) * 512 + ks * 32 + lg * 8);

  #pragma unroll
  for (int win = 0; win < 2; ++win) {
    char* ldw = lds + win * 32768;
    f32x4 o[2][4];
    #pragma unroll
    for (int it = 0; it < 2; ++it)
      #pragma unroll
      for (int dt = 0; dt < 4; ++dt) o[it][dt] = (f32x4){0.f, 0.f, 0.f, 0.f};
    #pragma unroll
    for (int ks = 0; ks < 2; ++ks) {
      bf16x8 vb[4], pa[2];
      #pragma unroll
      for (int dt = 0; dt < 4; ++dt) {
        int d = dt * 16 + lr;
        vb[dt] = *(const bf16x8*)(ldw + 16384 + hl * 8192 + d * 128 + ((ks * 64 + lg * 16) ^ swz(d, hl)));
      }
      #pragma unroll
      for (int it = 0; it < 2; ++it) {
        int i = (ih * 2 + it) * 16 + lr;
        pa[it] = *(const bf16x8*)(ldw + hl * 8192 + i * 128 + ((ks * 64 + lg * 16) ^ swz(i, hl)));
      }
      __builtin_amdgcn_s_setprio(1);
      #pragma unroll
      for (int it = 0; it < 2; ++it)
        #pragma unroll
        for (int dt = 0; dt < 4; ++dt)
          o[it][dt] = __builtin_amdgcn_mfma_f32_16x16x32_bf16(vb[dt], pa[it], o[it][dt], 0, 0, 0);
      __builtin_amdgcn_s_setprio(0);
    }
    #pragma unroll
    for (int it = 0; it < 2; ++it) {
      int i  = (ih * 2 + it) * 16 + lr;
      int lm = 8 * hl + (i >> 3);
      int rp = lm * 8 + (i & 7);
      #pragma unroll
      for (int dt = 0; dt < 4; ++dt) {
        s16x4 pk;
        #pragma unroll
        for (int r = 0; r < 4; ++r) pk[r] = f2bf(o[it][dt][r]);
        *(s16x4*)(ldw + rp * 128 + ((dt * 32 + lg * 8) ^ swz(rp, 0))) = pk;
      }
    }
  }
  __syncthreads();

  f32x4 oacc[2];
  oacc[0] = (f32x4){0.f, 0.f, 0.f, 0.f};
  oacc[1] = (f32x4){0.f, 0.f, 0.f, 0.f};
  #pragma unroll
  for (int ks = 0; ks < 16; ++ks) {
    int rp = lr * 8 + (ks >> 1);
    int boff = rp * 128 + (((ks & 1) * 64 + lg * 16) ^ swz(rp, 0));
    #pragma unroll
    for (int win = 0; win < 2; ++win) {
      bf16x8 bfrOH = *(const bf16x8*)(lds + win * 32768 + boff);
      oacc[win] = __builtin_amdgcn_mfma_f32_16x16x32_bf16(wofr[ks], bfrOH, oacc[win], 0, 0, 0);
    }
  }
  {
    int c0 = wv * 16 + lg * 4;
    float4 bo4 = *(const float4*)(bo + c0);
    int tok = 16 * hp + lr;
    #pragma unroll
    for (int win = 0; win < 2; ++win) {
      int sw = ww0a[win] + tok + 4; if (sw >= 192) sw -= 192;
      float4 ov;
      ov.x = oacc[win][0] + bo4.x; ov.y = oacc[win][1] + bo4.y;
      ov.z = oacc[win][2] + bo4.z; ov.w = oacc[win][3] + bo4.w;
      *(float4*)(orow[win] + sw * 64 + c0) = ov;
    }
  }
}

extern "C" void kernel_launch(void* const* d_in, const int* in_sizes, int n_in,
                              void* d_out, int out_size, void* d_ws, size_t ws_size,
                              hipStream_t stream) {
  const float* x    = (const float*)d_in[0];
  const float* Wq   = (const float*)d_in[1];
  const float* Wkv  = (const float*)d_in[2];
  const float* Wo   = (const float*)d_in[3];
  const float* bo   = (const float*)d_in[4];
  const float* pos  = (const float*)d_in[5];
  float* o = (float*)d_out;
  wmsa_prep<<<dim3(640), dim3(256), 0, stream>>>(Wq, Wkv, Wo, pos, (short*)d_ws);
  hipError_t e = hipFuncSetAttribute((const void*)wmsa_mfma4,
                                     hipFuncAttributeMaxDynamicSharedMemorySize, 131072);
  if (e == hipSuccess) {
    wmsa_mfma4<<<dim3(NWIN), dim3(512), 131072, stream>>>(x, bo, (const short*)d_ws, o);
  } else {
    wmsa_mfma<<<dim3(NWIN * 2), dim3(THREADS), 0, stream>>>(x, bo, (const short*)d_ws, o);
  }
}